// Round 5
// baseline (258.084 us; speedup 1.0000x reference)
//
#include <hip/hip_runtime.h>
#include <hip/hip_bf16.h>
#include <stdint.h>

// Problem constants
constexpr int cB = 2;
constexpr int cS = 2048;
constexpr int cH = 1024;
constexpr int cNH = 16;
constexpr int cHD = 64;
constexpr int cBS = cB * cS;  // 4096

typedef short short8 __attribute__((ext_vector_type(8)));
typedef float f32x4 __attribute__((ext_vector_type(4)));

__device__ inline unsigned short f2bf(float f) {
  union { float f; unsigned u; } v; v.f = f;
  unsigned r = v.u + 0x7FFF + ((v.u >> 16) & 1);  // RNE
  return (unsigned short)(r >> 16);
}

__device__ inline void gload_lds16(const void* g, void* l) {
  __builtin_amdgcn_global_load_lds(
      (const __attribute__((address_space(1))) void*)g,
      (__attribute__((address_space(3))) void*)l,
      16, 0, 0);
}

// ---------------- QKV GEMM: C[i,o] = sum_k X[i,k] * W[o,k] + b[o] ----------------
// fp32 inputs, bf16 output (Q/K/V scratch). Reg-staged LDS (f32x4 -> bf16 -> ds_write).
// 128x128 tile, BK=32, 4 waves (2x2), each wave 64x64 (4x4 MFMA frags).
constexpr int BM = 128, BN = 128, BK = 32;

__global__ __launch_bounds__(256) void qkv_gemm(
    const float* __restrict__ X,   // [4096][1024]
    const float* __restrict__ Wq,  // [1024][1024] (row=out, col=in)
    const float* __restrict__ Wk,
    const float* __restrict__ Wv,
    const float* __restrict__ bq, const float* __restrict__ bk,
    const float* __restrict__ bv,
    unsigned short* __restrict__ Qb, unsigned short* __restrict__ Kb,
    unsigned short* __restrict__ Vb) {
  __shared__ alignas(16) unsigned short As[BM * BK];  // [128][32]
  __shared__ alignas(16) unsigned short Bs[BN * BK];

  const int nb = blockIdx.x;  // 0..23
  const int mb = blockIdx.y;  // 0..31
  const int m0 = mb * BM;
  const int wsel = nb >> 3;
  const int n0 = (nb & 7) * BN;  // col within this W's 1024
  const float* W = (wsel == 0) ? Wq : (wsel == 1 ? Wk : Wv);
  const float* bias = (wsel == 0) ? bq : (wsel == 1 ? bk : bv);
  unsigned short* Out = (wsel == 0) ? Qb : (wsel == 1 ? Kb : Vb);

  const int t = threadIdx.x;
  const int w = t >> 6, l = t & 63, lr = l & 15, lg = l >> 4;
  const int wm = w >> 1, wn = w & 1;
  const int srow = t >> 1;
  const int scol = (t & 1) * 16;

  f32x4 acc[4][4];
#pragma unroll
  for (int mi = 0; mi < 4; ++mi)
#pragma unroll
    for (int ni = 0; ni < 4; ++ni) acc[mi][ni] = {0.f, 0.f, 0.f, 0.f};

  for (int kt = 0; kt < cH / BK; ++kt) {
    const int k0 = kt * BK;
    __syncthreads();
    {
      const float* s = X + (size_t)(m0 + srow) * cH + k0 + scol;
      f32x4 v0 = *reinterpret_cast<const f32x4*>(s);
      f32x4 v1 = *reinterpret_cast<const f32x4*>(s + 4);
      f32x4 v2 = *reinterpret_cast<const f32x4*>(s + 8);
      f32x4 v3 = *reinterpret_cast<const f32x4*>(s + 12);
      short8 o0, o1;
#pragma unroll
      for (int j = 0; j < 4; ++j) {
        o0[j] = (short)f2bf(v0[j]);
        o0[4 + j] = (short)f2bf(v1[j]);
        o1[j] = (short)f2bf(v2[j]);
        o1[4 + j] = (short)f2bf(v3[j]);
      }
      *reinterpret_cast<short8*>(&As[srow * BK + scol]) = o0;
      *reinterpret_cast<short8*>(&As[srow * BK + scol + 8]) = o1;
    }
    {
      const float* s = W + (size_t)(n0 + srow) * cH + k0 + scol;
      f32x4 v0 = *reinterpret_cast<const f32x4*>(s);
      f32x4 v1 = *reinterpret_cast<const f32x4*>(s + 4);
      f32x4 v2 = *reinterpret_cast<const f32x4*>(s + 8);
      f32x4 v3 = *reinterpret_cast<const f32x4*>(s + 12);
      short8 o0, o1;
#pragma unroll
      for (int j = 0; j < 4; ++j) {
        o0[j] = (short)f2bf(v0[j]);
        o0[4 + j] = (short)f2bf(v1[j]);
        o1[j] = (short)f2bf(v2[j]);
        o1[4 + j] = (short)f2bf(v3[j]);
      }
      *reinterpret_cast<short8*>(&Bs[srow * BK + scol]) = o0;
      *reinterpret_cast<short8*>(&Bs[srow * BK + scol + 8]) = o1;
    }
    __syncthreads();

    short8 af[4], bfr[4];
#pragma unroll
    for (int mi = 0; mi < 4; ++mi)
      af[mi] = *reinterpret_cast<const short8*>(
          &As[(wm * 64 + mi * 16 + lr) * BK + lg * 8]);
#pragma unroll
    for (int ni = 0; ni < 4; ++ni)
      bfr[ni] = *reinterpret_cast<const short8*>(
          &Bs[(wn * 64 + ni * 16 + lr) * BK + lg * 8]);
#pragma unroll
    for (int mi = 0; mi < 4; ++mi)
#pragma unroll
      for (int ni = 0; ni < 4; ++ni)
        acc[mi][ni] = __builtin_amdgcn_mfma_f32_16x16x32_bf16(
            af[mi], bfr[ni], acc[mi][ni], 0, 0, 0);
  }

#pragma unroll
  for (int ni = 0; ni < 4; ++ni) {
    const int col = n0 + wn * 64 + ni * 16 + lr;
    const float bvv = bias[col];
#pragma unroll
    for (int mi = 0; mi < 4; ++mi) {
      const int row = m0 + wm * 64 + mi * 16 + lg * 4;
#pragma unroll
      for (int r = 0; r < 4; ++r)
        Out[(size_t)(row + r) * cH + col] = f2bf(acc[mi][ni][r] + bvv);
    }
  }
}

// ---------------- Flash attention ----------------
// Block = (qb, bh): 64 q-rows of one (b,h). 4 waves x 16 q-rows each.
// K/V tiles (64 rows x 64 d) staged ONCE per block into double-buffered LDS:
//   K: row-major [64][64] with XOR swizzle byte^=((row&7)<<4), staged via
//      pre-swizzled per-lane global source granule, read as swizzled b128.
//   V: row-major [64][64] LINEAR (no swizzle), read as scalar u16 (safe;
//      known 8-way conflict -> r6 target).
// P-tile: per-wave [16][64] XOR-swizzled, protected by block barriers (r3).
// Online softmax per q-row across 16-lane groups. Output fp32.
__global__ __launch_bounds__(256) void attn_kernel(
    const unsigned short* __restrict__ Qb,  // [B*S][H] bf16
    const unsigned short* __restrict__ Kb,
    const unsigned short* __restrict__ Vb,
    const float* __restrict__ mask,         // [B][S]
    float* __restrict__ out) {              // [B*S][H] fp32
  __shared__ alignas(16) unsigned short Ks[2][64 * 64];    // 16 KB
  __shared__ alignas(16) unsigned short Vs[2][64 * 64];    // 16 KB
  __shared__ alignas(16) unsigned short plds[4][16 * 64];  // 8 KB, per-wave

  const int qb = blockIdx.x;  // 0..31
  const int bh = blockIdx.y;  // 0..31
  const int b = bh >> 4, h = bh & 15;
  const int t = threadIdx.x;
  const int w = t >> 6, l = t & 63, lr = l & 15, lg = l >> 4;
  const int q0 = qb * 64 + w * 16;

  const unsigned short* Kbase = Kb + (size_t)b * cS * cH + h * cHD;
  const unsigned short* Vbase = Vb + (size_t)b * cS * cH + h * cHD;
  const float* mbase = mask + b * cS;

  // Per-lane staging decode: granule g (16B) of the 8KB tile; wave w owns
  // shots 2w,2w+1 (each shot = 64 lanes x 16B = 1KB linear LDS dest).
  // K: physical granule (gr,gc) <- global row gr, granule col gc^(gr&7)
  //    (inverse of the read-side XOR). V: linear (row gr, col gc*8).
  int rK[2], cK[2];
#pragma unroll
  for (int s2 = 0; s2 < 2; ++s2) {
    const int g = (w * 2 + s2) * 64 + l;
    const int gr = g >> 3, gc = g & 7;
    rK[s2] = gr;
    cK[s2] = (gc ^ (gr & 7)) * 8;
  }

  const unsigned short* Qrow = Qb + (size_t)(b * cS + q0 + lr) * cH + h * cHD;
  short8 qf0 = *reinterpret_cast<const short8*>(Qrow + lg * 8);
  short8 qf1 = *reinterpret_cast<const short8*>(Qrow + 32 + lg * 8);

  f32x4 oacc[4];
#pragma unroll
  for (int d16 = 0; d16 < 4; ++d16) oacc[d16] = {0.f, 0.f, 0.f, 0.f};
  float mrow[4] = {-1e30f, -1e30f, -1e30f, -1e30f};
  float lsum[4] = {0.f, 0.f, 0.f, 0.f};

  auto stage = [&](int bufi, int kv0) {
#pragma unroll
    for (int s2 = 0; s2 < 2; ++s2) {
      const int g = (w * 2 + s2) * 64 + l;
      gload_lds16(Kbase + (size_t)(kv0 + rK[s2]) * cH + cK[s2],
                  (char*)&Ks[bufi][0] + (w * 2 + s2) * 1024);
      gload_lds16(Vbase + (size_t)(kv0 + (g >> 3)) * cH + (g & 7) * 8,
                  (char*)&Vs[bufi][0] + (w * 2 + s2) * 1024);
    }
  };

  stage(0, 0);
  asm volatile("s_waitcnt vmcnt(0)" ::: "memory");
  __syncthreads();

  constexpr int NT = cS / 64;  // 32
  for (int kt = 0; kt < NT; ++kt) {
    const int bufi = kt & 1;
    if (kt + 1 < NT) stage(bufi ^ 1, (kt + 1) * 64);

    const unsigned short* Kt = &Ks[bufi][0];
    const unsigned short* Vt = &Vs[bufi][0];
    const int kv0 = kt * 64;

    // ---- QK^T from swizzled K LDS ----
    f32x4 sc[4];
#pragma unroll
    for (int n = 0; n < 4; ++n) {
      const int kr = n * 16 + lr;
      const unsigned sw = (unsigned)((kr & 7) << 4);
      const unsigned b0 = ((unsigned)(kr * 128 + lg * 16)) ^ sw;
      const unsigned b1 = ((unsigned)(kr * 128 + 64 + lg * 16)) ^ sw;
      short8 kf0 = *reinterpret_cast<const short8*>((const char*)Kt + b0);
      short8 kf1 = *reinterpret_cast<const short8*>((const char*)Kt + b1);
      f32x4 z = {0.f, 0.f, 0.f, 0.f};
      z = __builtin_amdgcn_mfma_f32_16x16x32_bf16(qf0, kf0, z, 0, 0, 0);
      z = __builtin_amdgcn_mfma_f32_16x16x32_bf16(qf1, kf1, z, 0, 0, 0);
      sc[n] = z * 0.125f + mbase[kv0 + kr];
    }

    // ---- online softmax (q-row lg*4+r spread over the 16 lanes sharing lg) ----
    float scalef[4];
    unsigned short pb[4][4];  // [n][r]
#pragma unroll
    for (int r = 0; r < 4; ++r) {
      float mx = fmaxf(fmaxf(sc[0][r], sc[1][r]), fmaxf(sc[2][r], sc[3][r]));
#pragma unroll
      for (int d = 1; d < 16; d <<= 1) mx = fmaxf(mx, __shfl_xor(mx, d));
      const float mnew = fmaxf(mrow[r], mx);
      scalef[r] = __expf(mrow[r] - mnew);
      mrow[r] = mnew;
      float ps = 0.f;
#pragma unroll
      for (int n = 0; n < 4; ++n) {
        const float p = __expf(sc[n][r] - mnew);
        ps += p;
        pb[n][r] = f2bf(p);
      }
#pragma unroll
      for (int d = 1; d < 16; d <<= 1) ps += __shfl_xor(ps, d);
      lsum[r] = lsum[r] * scalef[r] + ps;
    }
#pragma unroll
    for (int d16 = 0; d16 < 4; ++d16)
#pragma unroll
      for (int r = 0; r < 4; ++r) oacc[d16][r] *= scalef[r];

    // ---- P -> per-wave LDS tile [16][64], XOR-swizzled; block barriers for
    //      bulletproof ordering (r3 structure) ----
    __syncthreads();
    char* pw = (char*)&plds[w][0];
#pragma unroll
    for (int r = 0; r < 4; ++r) {
      const int prow = lg * 4 + r;
      const unsigned swp = (unsigned)((prow & 7) << 4);
#pragma unroll
      for (int n = 0; n < 4; ++n) {
        const unsigned byt = ((unsigned)(prow * 128 + (n * 16 + lr) * 2)) ^ swp;
        *reinterpret_cast<unsigned short*>(pw + byt) = pb[n][r];
      }
    }
    __syncthreads();

    // ---- PV: A = P (swizzled b128), B = V via scalar LDS reads ----
#pragma unroll
    for (int ks2 = 0; ks2 < 2; ++ks2) {
      const unsigned pby = ((unsigned)(lr * 128 + ks2 * 64 + lg * 16)) ^
                           ((unsigned)((lr & 7) << 4));
      short8 pa = *reinterpret_cast<const short8*>(pw + pby);
      const unsigned short* vb0 = Vt + (ks2 * 32 + lg * 8) * 64 + lr;
#pragma unroll
      for (int d16 = 0; d16 < 4; ++d16) {
        short8 vf;
#pragma unroll
        for (int j = 0; j < 8; ++j) vf[j] = (short)vb0[j * 64 + d16 * 16];
        oacc[d16] =
            __builtin_amdgcn_mfma_f32_16x16x32_bf16(pa, vf, oacc[d16], 0, 0, 0);
      }
    }

    asm volatile("s_waitcnt vmcnt(0)" ::: "memory");
    __syncthreads();  // staged tile kt+1 ready; all waves done with buf kt
  }

  // fp32 store
  float* obase = out + (size_t)(b * cS + q0 + lg * 4) * cH + h * cHD;
#pragma unroll
  for (int r = 0; r < 4; ++r) {
    const float inv = 1.0f / lsum[r];
#pragma unroll
    for (int d16 = 0; d16 < 4; ++d16)
      obase[(size_t)r * cH + d16 * 16 + lr] = oacc[d16][r] * inv;
  }
}

// ---------------- launcher ----------------
extern "C" void kernel_launch(void* const* d_in, const int* in_sizes, int n_in,
                              void* d_out, int out_size, void* d_ws,
                              size_t ws_size, hipStream_t stream) {
  const float* X = (const float*)d_in[0];     // [B,S,H]
  const float* mask = (const float*)d_in[1];  // [B,1,1,S]
  const float* Wq = (const float*)d_in[2];
  const float* bq = (const float*)d_in[3];
  const float* Wk = (const float*)d_in[4];
  const float* bk = (const float*)d_in[5];
  const float* Wv = (const float*)d_in[6];
  const float* bv = (const float*)d_in[7];
  float* outp = (float*)d_out;  // fp32 (reference output dtype)

  // workspace: Q,K,V bf16 -> 24 MB total
  char* ws = (char*)d_ws;
  const size_t MB = 1 << 20;
  unsigned short* Qb = (unsigned short*)(ws + 0 * MB);   // 8 MB
  unsigned short* Kb = (unsigned short*)(ws + 8 * MB);   // 8 MB
  unsigned short* Vb = (unsigned short*)(ws + 16 * MB);  // 8 MB

  qkv_gemm<<<dim3(24, 32), 256, 0, stream>>>(X, Wq, Wk, Wv, bq, bk, bv, Qb, Kb,
                                             Vb);
  attn_kernel<<<dim3(32, 32), 256, 0, stream>>>(Qb, Kb, Vb, mask, outp);
}

// Round 7
// 235.003 us; speedup vs baseline: 1.0982x; 1.0982x over previous
//
#include <hip/hip_runtime.h>
#include <hip/hip_bf16.h>
#include <stdint.h>

// Problem constants
constexpr int cB = 2;
constexpr int cS = 2048;
constexpr int cH = 1024;
constexpr int cNH = 16;
constexpr int cHD = 64;
constexpr int cBS = cB * cS;  // 4096

typedef short short8 __attribute__((ext_vector_type(8)));
typedef short short4v __attribute__((ext_vector_type(4)));
typedef float f32x4 __attribute__((ext_vector_type(4)));

__device__ inline unsigned short f2bf(float f) {
  union { float f; unsigned u; } v; v.f = f;
  unsigned r = v.u + 0x7FFF + ((v.u >> 16) & 1);  // RNE
  return (unsigned short)(r >> 16);
}

__device__ inline void gload_lds16(const void* g, void* l) {
  __builtin_amdgcn_global_load_lds(
      (const __attribute__((address_space(1))) void*)g,
      (__attribute__((address_space(3))) void*)l,
      16, 0, 0);
}

// ds_read_b64_tr_b16 semantics (m156+m162 reconciled): each lane does a plain
// 64b read (4 consecutive bf16) at its OWN addr; HW transposes within each
// 16-lane group: group's reads form a 4x16 tile T (lane s holds
// T[s>>2][(s&3)*4..+4)); lane a receives column a of T (elem j = T[j][a]).
__device__ inline short4v tr16(const unsigned short* p) {
  short4v d;
  auto p3 = (const __attribute__((address_space(3))) unsigned short*)p;
  asm volatile("ds_read_b64_tr_b16 %0, %1" : "=v"(d) : "v"(p3) : "memory");
  return d;
}

// ---------------- QKV GEMM: C[i,o] = sum_k X[i,k] * W[o,k] + b[o] ----------------
// fp32 inputs, bf16 output (Q/K/V scratch). Reg-staged LDS (f32x4 -> bf16 -> ds_write).
// 128x128 tile, BK=32, 4 waves (2x2), each wave 64x64 (4x4 MFMA frags).
constexpr int BM = 128, BN = 128, BK = 32;

__global__ __launch_bounds__(256) void qkv_gemm(
    const float* __restrict__ X,   // [4096][1024]
    const float* __restrict__ Wq,  // [1024][1024] (row=out, col=in)
    const float* __restrict__ Wk,
    const float* __restrict__ Wv,
    const float* __restrict__ bq, const float* __restrict__ bk,
    const float* __restrict__ bv,
    unsigned short* __restrict__ Qb, unsigned short* __restrict__ Kb,
    unsigned short* __restrict__ Vb) {
  __shared__ alignas(16) unsigned short As[BM * BK];  // [128][32]
  __shared__ alignas(16) unsigned short Bs[BN * BK];

  const int nb = blockIdx.x;  // 0..23
  const int mb = blockIdx.y;  // 0..31
  const int m0 = mb * BM;
  const int wsel = nb >> 3;
  const int n0 = (nb & 7) * BN;  // col within this W's 1024
  const float* W = (wsel == 0) ? Wq : (wsel == 1 ? Wk : Wv);
  const float* bias = (wsel == 0) ? bq : (wsel == 1 ? bk : bv);
  unsigned short* Out = (wsel == 0) ? Qb : (wsel == 1 ? Kb : Vb);

  const int t = threadIdx.x;
  const int w = t >> 6, l = t & 63, lr = l & 15, lg = l >> 4;
  const int wm = w >> 1, wn = w & 1;
  const int srow = t >> 1;
  const int scol = (t & 1) * 16;

  f32x4 acc[4][4];
#pragma unroll
  for (int mi = 0; mi < 4; ++mi)
#pragma unroll
    for (int ni = 0; ni < 4; ++ni) acc[mi][ni] = {0.f, 0.f, 0.f, 0.f};

  for (int kt = 0; kt < cH / BK; ++kt) {
    const int k0 = kt * BK;
    __syncthreads();
    {
      const float* s = X + (size_t)(m0 + srow) * cH + k0 + scol;
      f32x4 v0 = *reinterpret_cast<const f32x4*>(s);
      f32x4 v1 = *reinterpret_cast<const f32x4*>(s + 4);
      f32x4 v2 = *reinterpret_cast<const f32x4*>(s + 8);
      f32x4 v3 = *reinterpret_cast<const f32x4*>(s + 12);
      short8 o0, o1;
#pragma unroll
      for (int j = 0; j < 4; ++j) {
        o0[j] = (short)f2bf(v0[j]);
        o0[4 + j] = (short)f2bf(v1[j]);
        o1[j] = (short)f2bf(v2[j]);
        o1[4 + j] = (short)f2bf(v3[j]);
      }
      *reinterpret_cast<short8*>(&As[srow * BK + scol]) = o0;
      *reinterpret_cast<short8*>(&As[srow * BK + scol + 8]) = o1;
    }
    {
      const float* s = W + (size_t)(n0 + srow) * cH + k0 + scol;
      f32x4 v0 = *reinterpret_cast<const f32x4*>(s);
      f32x4 v1 = *reinterpret_cast<const f32x4*>(s + 4);
      f32x4 v2 = *reinterpret_cast<const f32x4*>(s + 8);
      f32x4 v3 = *reinterpret_cast<const f32x4*>(s + 12);
      short8 o0, o1;
#pragma unroll
      for (int j = 0; j < 4; ++j) {
        o0[j] = (short)f2bf(v0[j]);
        o0[4 + j] = (short)f2bf(v1[j]);
        o1[j] = (short)f2bf(v2[j]);
        o1[4 + j] = (short)f2bf(v3[j]);
      }
      *reinterpret_cast<short8*>(&Bs[srow * BK + scol]) = o0;
      *reinterpret_cast<short8*>(&Bs[srow * BK + scol + 8]) = o1;
    }
    __syncthreads();

    short8 af[4], bfr[4];
#pragma unroll
    for (int mi = 0; mi < 4; ++mi)
      af[mi] = *reinterpret_cast<const short8*>(
          &As[(wm * 64 + mi * 16 + lr) * BK + lg * 8]);
#pragma unroll
    for (int ni = 0; ni < 4; ++ni)
      bfr[ni] = *reinterpret_cast<const short8*>(
          &Bs[(wn * 64 + ni * 16 + lr) * BK + lg * 8]);
#pragma unroll
    for (int mi = 0; mi < 4; ++mi)
#pragma unroll
      for (int ni = 0; ni < 4; ++ni)
        acc[mi][ni] = __builtin_amdgcn_mfma_f32_16x16x32_bf16(
            af[mi], bfr[ni], acc[mi][ni], 0, 0, 0);
  }

#pragma unroll
  for (int ni = 0; ni < 4; ++ni) {
    const int col = n0 + wn * 64 + ni * 16 + lr;
    const float bvv = bias[col];
#pragma unroll
    for (int mi = 0; mi < 4; ++mi) {
      const int row = m0 + wm * 64 + mi * 16 + lg * 4;
#pragma unroll
      for (int r = 0; r < 4; ++r)
        Out[(size_t)(row + r) * cH + col] = f2bf(acc[mi][ni][r] + bvv);
    }
  }
}

// ---------------- Flash attention ----------------
// Block = (qb, bh): 64 q-rows of one (b,h). 4 waves x 16 q-rows each.
// K/V tiles (64 rows x 64 d) staged ONCE per block into double-buffered LDS:
//   K: row-major [64][64] with XOR swizzle byte^=((row&7)<<4), staged via
//      pre-swizzled per-lane global source granule, read as swizzled b128.
//   V: subtiled [kvb=16][db=4][4][16]; elem offset of V[r][c] =
//      (r>>2)*256+(c>>4)*64+(r&3)*16+(c&15). PV B-fragments via tr16:
//      group lg reads a contiguous 128B run (lane lr at +lr*4 elems),
//      HW delivers column lr of the 4x16 tile.
// P-tile: per-wave [16][64] XOR-swizzled, protected by block barriers (r5).
// Online softmax per q-row across 16-lane groups. Output fp32.
__global__ __launch_bounds__(256) void attn_kernel(
    const unsigned short* __restrict__ Qb,  // [B*S][H] bf16
    const unsigned short* __restrict__ Kb,
    const unsigned short* __restrict__ Vb,
    const float* __restrict__ mask,         // [B][S]
    float* __restrict__ out) {              // [B*S][H] fp32
  __shared__ alignas(16) unsigned short Ks[2][64 * 64];    // 16 KB
  __shared__ alignas(16) unsigned short Vs[2][64 * 64];    // 16 KB
  __shared__ alignas(16) unsigned short plds[4][16 * 64];  // 8 KB, per-wave

  const int qb = blockIdx.x;  // 0..31
  const int bh = blockIdx.y;  // 0..31
  const int b = bh >> 4, h = bh & 15;
  const int t = threadIdx.x;
  const int w = t >> 6, l = t & 63, lr = l & 15, lg = l >> 4;
  const int q0 = qb * 64 + w * 16;

  const unsigned short* Kbase = Kb + (size_t)b * cS * cH + h * cHD;
  const unsigned short* Vbase = Vb + (size_t)b * cS * cH + h * cHD;
  const float* mbase = mask + b * cS;

  // Per-lane staging decode: granule g (16B) of the 8KB tile; wave w owns
  // shots 2w,2w+1 (each shot = 64 lanes x 16B = 1KB linear LDS dest).
  // K: physical granule (gr,gc) <- global row gr, granule col gc^(gr&7).
  // V: granule (gr,gc) <- global row (gr>>2)*4+(gc>>1), col (gr&3)*16+(gc&1)*8.
  int rK[2], cK[2], rV[2], cV[2];
#pragma unroll
  for (int s2 = 0; s2 < 2; ++s2) {
    const int g = (w * 2 + s2) * 64 + l;
    const int gr = g >> 3, gc = g & 7;
    rK[s2] = gr;
    cK[s2] = (gc ^ (gr & 7)) * 8;
    rV[s2] = (gr >> 2) * 4 + (gc >> 1);
    cV[s2] = (gr & 3) * 16 + (gc & 1) * 8;
  }

  const unsigned short* Qrow = Qb + (size_t)(b * cS + q0 + lr) * cH + h * cHD;
  short8 qf0 = *reinterpret_cast<const short8*>(Qrow + lg * 8);
  short8 qf1 = *reinterpret_cast<const short8*>(Qrow + 32 + lg * 8);

  f32x4 oacc[4];
#pragma unroll
  for (int d16 = 0; d16 < 4; ++d16) oacc[d16] = {0.f, 0.f, 0.f, 0.f};
  float mrow[4] = {-1e30f, -1e30f, -1e30f, -1e30f};
  float lsum[4] = {0.f, 0.f, 0.f, 0.f};

  auto stage = [&](int bufi, int kv0) {
#pragma unroll
    for (int s2 = 0; s2 < 2; ++s2) {
      gload_lds16(Kbase + (size_t)(kv0 + rK[s2]) * cH + cK[s2],
                  (char*)&Ks[bufi][0] + (w * 2 + s2) * 1024);
      gload_lds16(Vbase + (size_t)(kv0 + rV[s2]) * cH + cV[s2],
                  (char*)&Vs[bufi][0] + (w * 2 + s2) * 1024);
    }
  };

  stage(0, 0);
  asm volatile("s_waitcnt vmcnt(0)" ::: "memory");
  __syncthreads();

  constexpr int NT = cS / 64;  // 32
  for (int kt = 0; kt < NT; ++kt) {
    const int bufi = kt & 1;
    if (kt + 1 < NT) stage(bufi ^ 1, (kt + 1) * 64);

    const unsigned short* Kt = &Ks[bufi][0];
    const unsigned short* Vt = &Vs[bufi][0];
    const int kv0 = kt * 64;

    // ---- QK^T from swizzled K LDS ----
    f32x4 sc[4];
#pragma unroll
    for (int n = 0; n < 4; ++n) {
      const int kr = n * 16 + lr;
      const unsigned sw = (unsigned)((kr & 7) << 4);
      const unsigned b0 = ((unsigned)(kr * 128 + lg * 16)) ^ sw;
      const unsigned b1 = ((unsigned)(kr * 128 + 64 + lg * 16)) ^ sw;
      short8 kf0 = *reinterpret_cast<const short8*>((const char*)Kt + b0);
      short8 kf1 = *reinterpret_cast<const short8*>((const char*)Kt + b1);
      f32x4 z = {0.f, 0.f, 0.f, 0.f};
      z = __builtin_amdgcn_mfma_f32_16x16x32_bf16(qf0, kf0, z, 0, 0, 0);
      z = __builtin_amdgcn_mfma_f32_16x16x32_bf16(qf1, kf1, z, 0, 0, 0);
      sc[n] = z * 0.125f + mbase[kv0 + kr];
    }

    // ---- online softmax (q-row lg*4+r spread over the 16 lanes sharing lg) ----
    float scalef[4];
    unsigned short pb[4][4];  // [n][r]
#pragma unroll
    for (int r = 0; r < 4; ++r) {
      float mx = fmaxf(fmaxf(sc[0][r], sc[1][r]), fmaxf(sc[2][r], sc[3][r]));
#pragma unroll
      for (int d = 1; d < 16; d <<= 1) mx = fmaxf(mx, __shfl_xor(mx, d));
      const float mnew = fmaxf(mrow[r], mx);
      scalef[r] = __expf(mrow[r] - mnew);
      mrow[r] = mnew;
      float ps = 0.f;
#pragma unroll
      for (int n = 0; n < 4; ++n) {
        const float p = __expf(sc[n][r] - mnew);
        ps += p;
        pb[n][r] = f2bf(p);
      }
#pragma unroll
      for (int d = 1; d < 16; d <<= 1) ps += __shfl_xor(ps, d);
      lsum[r] = lsum[r] * scalef[r] + ps;
    }
#pragma unroll
    for (int d16 = 0; d16 < 4; ++d16)
#pragma unroll
      for (int r = 0; r < 4; ++r) oacc[d16][r] *= scalef[r];

    // ---- P -> per-wave LDS tile [16][64], XOR-swizzled; block barriers for
    //      bulletproof ordering (r5 structure) ----
    __syncthreads();
    char* pw = (char*)&plds[w][0];
#pragma unroll
    for (int r = 0; r < 4; ++r) {
      const int prow = lg * 4 + r;
      const unsigned swp = (unsigned)((prow & 7) << 4);
#pragma unroll
      for (int n = 0; n < 4; ++n) {
        const unsigned byt = ((unsigned)(prow * 128 + (n * 16 + lr) * 2)) ^ swp;
        *reinterpret_cast<unsigned short*>(pw + byt) = pb[n][r];
      }
    }
    __syncthreads();

    // ---- PV: A = P (swizzled b128), B = V via hardware transpose reads ----
#pragma unroll
    for (int ks2 = 0; ks2 < 2; ++ks2) {
      const unsigned pby = ((unsigned)(lr * 128 + ks2 * 64 + lg * 16)) ^
                           ((unsigned)((lr & 7) << 4));
      short8 pa = *reinterpret_cast<const short8*>(pw + pby);
      // Need vf[j] = V[k0+j][d16*16+lr], k0 = ks2*32+lg*8. Group lg's 4x16
      // tile T[j][a] = V[k0+j][d16*16+a]; lane lr supplies T rows via a
      // contiguous 8B chunk at subtiled elem offset:
      //   (ks2*8+lg*2)*256 + d16*64 + lr*4   (rows k0..k0+3)
      //   +256                               (rows k0+4..k0+7)
      short4v tv[8];
#pragma unroll
      for (int d16 = 0; d16 < 4; ++d16) {
        const unsigned short* a0 =
            Vt + (ks2 * 8 + lg * 2) * 256 + d16 * 64 + lr * 4;
        tv[2 * d16] = tr16(a0);            // delivers rows k0..+3, col lr
        tv[2 * d16 + 1] = tr16(a0 + 256);  // rows k0+4..+7, col lr
      }
      asm volatile("s_waitcnt lgkmcnt(0)" ::: "memory");
      __builtin_amdgcn_sched_barrier(0);
#pragma unroll
      for (int d16 = 0; d16 < 4; ++d16) {
        short8 vf;
#pragma unroll
        for (int j = 0; j < 4; ++j) {
          vf[j] = tv[2 * d16][j];
          vf[4 + j] = tv[2 * d16 + 1][j];
        }
        oacc[d16] =
            __builtin_amdgcn_mfma_f32_16x16x32_bf16(pa, vf, oacc[d16], 0, 0, 0);
      }
    }

    asm volatile("s_waitcnt vmcnt(0)" ::: "memory");
    __syncthreads();  // staged tile kt+1 ready; all waves done with buf kt
  }

  // fp32 store
  float* obase = out + (size_t)(b * cS + q0 + lg * 4) * cH + h * cHD;
#pragma unroll
  for (int r = 0; r < 4; ++r) {
    const float inv = 1.0f / lsum[r];
#pragma unroll
    for (int d16 = 0; d16 < 4; ++d16)
      obase[(size_t)r * cH + d16 * 16 + lr] = oacc[d16][r] * inv;
  }
}

// ---------------- launcher ----------------
extern "C" void kernel_launch(void* const* d_in, const int* in_sizes, int n_in,
                              void* d_out, int out_size, void* d_ws,
                              size_t ws_size, hipStream_t stream) {
  const float* X = (const float*)d_in[0];     // [B,S,H]
  const float* mask = (const float*)d_in[1];  // [B,1,1,S]
  const float* Wq = (const float*)d_in[2];
  const float* bq = (const float*)d_in[3];
  const float* Wk = (const float*)d_in[4];
  const float* bk = (const float*)d_in[5];
  const float* Wv = (const float*)d_in[6];
  const float* bv = (const float*)d_in[7];
  float* outp = (float*)d_out;  // fp32 (reference output dtype)

  // workspace: Q,K,V bf16 -> 24 MB total
  char* ws = (char*)d_ws;
  const size_t MB = 1 << 20;
  unsigned short* Qb = (unsigned short*)(ws + 0 * MB);   // 8 MB
  unsigned short* Kb = (unsigned short*)(ws + 8 * MB);   // 8 MB
  unsigned short* Vb = (unsigned short*)(ws + 16 * MB);  // 8 MB

  qkv_gemm<<<dim3(24, 32), 256, 0, stream>>>(X, Wq, Wk, Wv, bq, bk, bv, Qb, Kb,
                                             Vb);
  attn_kernel<<<dim3(32, 32), 256, 0, stream>>>(Qb, Kb, Vb, mask, outp);
}

// Round 8
// 159.207 us; speedup vs baseline: 1.6211x; 1.4761x over previous
//
#include <hip/hip_runtime.h>
#include <hip/hip_bf16.h>
#include <stdint.h>

// Problem constants
constexpr int cB = 2;
constexpr int cS = 2048;
constexpr int cH = 1024;
constexpr int cNH = 16;
constexpr int cHD = 64;
constexpr int cBS = cB * cS;  // 4096

typedef short short8 __attribute__((ext_vector_type(8)));
typedef short short4v __attribute__((ext_vector_type(4)));
typedef float f32x4 __attribute__((ext_vector_type(4)));

__device__ inline unsigned short f2bf(float f) {
  union { float f; unsigned u; } v; v.f = f;
  unsigned r = v.u + 0x7FFF + ((v.u >> 16) & 1);  // RNE
  return (unsigned short)(r >> 16);
}

__device__ inline void gload_lds16(const void* g, void* l) {
  __builtin_amdgcn_global_load_lds(
      (const __attribute__((address_space(1))) void*)g,
      (__attribute__((address_space(3))) void*)l,
      16, 0, 0);
}

// ds_read_b64_tr_b16 (verified r7): each lane does a plain 64b read (4
// consecutive bf16) at its OWN addr; HW transposes within each 16-lane
// group: the group's reads form a 4x16 tile T (lane s supplies
// T[s>>2][(s&3)*4..+4)); lane a receives column a (elem j = T[j][a]).
__device__ inline short4v tr16(const unsigned short* p) {
  short4v d;
  auto p3 = (const __attribute__((address_space(3))) unsigned short*)p;
  asm volatile("ds_read_b64_tr_b16 %0, %1" : "=v"(d) : "v"(p3) : "memory");
  return d;
}

// ---------------- QKV GEMM: C[i,o] = sum_k X[i,k] * W[o,k] + b[o] ----------------
// fp32 inputs, bf16 output (Q/K/V scratch). Reg-staged LDS (f32x4 -> bf16 -> ds_write).
// 128x128 tile, BK=32, 4 waves (2x2), each wave 64x64 (4x4 MFMA frags).
constexpr int BM = 128, BN = 128, BK = 32;

__global__ __launch_bounds__(256) void qkv_gemm(
    const float* __restrict__ X,   // [4096][1024]
    const float* __restrict__ Wq,  // [1024][1024] (row=out, col=in)
    const float* __restrict__ Wk,
    const float* __restrict__ Wv,
    const float* __restrict__ bq, const float* __restrict__ bk,
    const float* __restrict__ bv,
    unsigned short* __restrict__ Qb, unsigned short* __restrict__ Kb,
    unsigned short* __restrict__ Vb) {
  __shared__ alignas(16) unsigned short As[BM * BK];  // [128][32]
  __shared__ alignas(16) unsigned short Bs[BN * BK];

  const int nb = blockIdx.x;  // 0..23
  const int mb = blockIdx.y;  // 0..31
  const int m0 = mb * BM;
  const int wsel = nb >> 3;
  const int n0 = (nb & 7) * BN;  // col within this W's 1024
  const float* W = (wsel == 0) ? Wq : (wsel == 1 ? Wk : Wv);
  const float* bias = (wsel == 0) ? bq : (wsel == 1 ? bk : bv);
  unsigned short* Out = (wsel == 0) ? Qb : (wsel == 1 ? Kb : Vb);

  const int t = threadIdx.x;
  const int w = t >> 6, l = t & 63, lr = l & 15, lg = l >> 4;
  const int wm = w >> 1, wn = w & 1;
  const int srow = t >> 1;
  const int scol = (t & 1) * 16;

  f32x4 acc[4][4];
#pragma unroll
  for (int mi = 0; mi < 4; ++mi)
#pragma unroll
    for (int ni = 0; ni < 4; ++ni) acc[mi][ni] = {0.f, 0.f, 0.f, 0.f};

  for (int kt = 0; kt < cH / BK; ++kt) {
    const int k0 = kt * BK;
    __syncthreads();
    {
      const float* s = X + (size_t)(m0 + srow) * cH + k0 + scol;
      f32x4 v0 = *reinterpret_cast<const f32x4*>(s);
      f32x4 v1 = *reinterpret_cast<const f32x4*>(s + 4);
      f32x4 v2 = *reinterpret_cast<const f32x4*>(s + 8);
      f32x4 v3 = *reinterpret_cast<const f32x4*>(s + 12);
      short8 o0, o1;
#pragma unroll
      for (int j = 0; j < 4; ++j) {
        o0[j] = (short)f2bf(v0[j]);
        o0[4 + j] = (short)f2bf(v1[j]);
        o1[j] = (short)f2bf(v2[j]);
        o1[4 + j] = (short)f2bf(v3[j]);
      }
      *reinterpret_cast<short8*>(&As[srow * BK + scol]) = o0;
      *reinterpret_cast<short8*>(&As[srow * BK + scol + 8]) = o1;
    }
    {
      const float* s = W + (size_t)(n0 + srow) * cH + k0 + scol;
      f32x4 v0 = *reinterpret_cast<const f32x4*>(s);
      f32x4 v1 = *reinterpret_cast<const f32x4*>(s + 4);
      f32x4 v2 = *reinterpret_cast<const f32x4*>(s + 8);
      f32x4 v3 = *reinterpret_cast<const f32x4*>(s + 12);
      short8 o0, o1;
#pragma unroll
      for (int j = 0; j < 4; ++j) {
        o0[j] = (short)f2bf(v0[j]);
        o0[4 + j] = (short)f2bf(v1[j]);
        o1[j] = (short)f2bf(v2[j]);
        o1[4 + j] = (short)f2bf(v3[j]);
      }
      *reinterpret_cast<short8*>(&Bs[srow * BK + scol]) = o0;
      *reinterpret_cast<short8*>(&Bs[srow * BK + scol + 8]) = o1;
    }
    __syncthreads();

    short8 af[4], bfr[4];
#pragma unroll
    for (int mi = 0; mi < 4; ++mi)
      af[mi] = *reinterpret_cast<const short8*>(
          &As[(wm * 64 + mi * 16 + lr) * BK + lg * 8]);
#pragma unroll
    for (int ni = 0; ni < 4; ++ni)
      bfr[ni] = *reinterpret_cast<const short8*>(
          &Bs[(wn * 64 + ni * 16 + lr) * BK + lg * 8]);
#pragma unroll
    for (int mi = 0; mi < 4; ++mi)
#pragma unroll
      for (int ni = 0; ni < 4; ++ni)
        acc[mi][ni] = __builtin_amdgcn_mfma_f32_16x16x32_bf16(
            af[mi], bfr[ni], acc[mi][ni], 0, 0, 0);
  }

#pragma unroll
  for (int ni = 0; ni < 4; ++ni) {
    const int col = n0 + wn * 64 + ni * 16 + lr;
    const float bvv = bias[col];
#pragma unroll
    for (int mi = 0; mi < 4; ++mi) {
      const int row = m0 + wm * 64 + mi * 16 + lg * 4;
#pragma unroll
      for (int r = 0; r < 4; ++r)
        Out[(size_t)(row + r) * cH + col] = f2bf(acc[mi][ni][r] + bvv);
    }
  }
}

// ---------------- Flash attention ----------------
// Block = (qb, bh): 64 q-rows of one (b,h). 4 waves x 16 q-rows each.
// K/V tiles (64x64) staged once per block into double-buffered LDS (r7).
// NEW r8: softmax row-sum via MFMA(pa, ones); P stored TRANSPOSED pT[64][16]
// per wave (4x ds_write_b64 swizzled, 4x tr16 read); no P barriers
// (per-wave tile + lgkmcnt/sched_barrier ordering). 1 block barrier/iter.
__global__ __launch_bounds__(256) void attn_kernel(
    const unsigned short* __restrict__ Qb,  // [B*S][H] bf16
    const unsigned short* __restrict__ Kb,
    const unsigned short* __restrict__ Vb,
    const float* __restrict__ mask,         // [B][S]
    float* __restrict__ out) {              // [B*S][H] fp32
  __shared__ alignas(16) unsigned short Ks[2][64 * 64];    // 16 KB
  __shared__ alignas(16) unsigned short Vs[2][64 * 64];    // 16 KB
  __shared__ alignas(16) unsigned short plds[4][64 * 16];  // 8 KB, per-wave pT

  const int qb = blockIdx.x;  // 0..31
  const int bh = blockIdx.y;  // 0..31
  const int b = bh >> 4, h = bh & 15;
  const int t = threadIdx.x;
  const int w = t >> 6, l = t & 63, lr = l & 15, lg = l >> 4;
  const int q0 = qb * 64 + w * 16;

  const unsigned short* Kbase = Kb + (size_t)b * cS * cH + h * cHD;
  const unsigned short* Vbase = Vb + (size_t)b * cS * cH + h * cHD;
  const float* mbase = mask + b * cS;

  // Staging decode (r7-verified): granule g (16B) of the 8KB tile; wave w
  // owns shots 2w,2w+1 (linear LDS dest).
  int rK[2], cK[2], rV[2], cV[2];
#pragma unroll
  for (int s2 = 0; s2 < 2; ++s2) {
    const int g = (w * 2 + s2) * 64 + l;
    const int gr = g >> 3, gc = g & 7;
    rK[s2] = gr;
    cK[s2] = (gc ^ (gr & 7)) * 8;
    rV[s2] = (gr >> 2) * 4 + (gc >> 1);
    cV[s2] = (gr & 3) * 16 + (gc & 1) * 8;
  }

  const unsigned short* Qrow = Qb + (size_t)(b * cS + q0 + lr) * cH + h * cHD;
  short8 qf0 = *reinterpret_cast<const short8*>(Qrow + lg * 8);
  short8 qf1 = *reinterpret_cast<const short8*>(Qrow + 32 + lg * 8);

  // ones B-frag (bf16 1.0 = 0x3F80) for the row-sum MFMA
  short8 ones;
#pragma unroll
  for (int j = 0; j < 8; ++j) ones[j] = (short)0x3F80;

  f32x4 oacc[4];
#pragma unroll
  for (int d16 = 0; d16 < 4; ++d16) oacc[d16] = {0.f, 0.f, 0.f, 0.f};
  f32x4 osum = {0.f, 0.f, 0.f, 0.f};
  float mrow[4] = {-1e30f, -1e30f, -1e30f, -1e30f};

  auto stage = [&](int bufi, int kv0) {
#pragma unroll
    for (int s2 = 0; s2 < 2; ++s2) {
      gload_lds16(Kbase + (size_t)(kv0 + rK[s2]) * cH + cK[s2],
                  (char*)&Ks[bufi][0] + (w * 2 + s2) * 1024);
      gload_lds16(Vbase + (size_t)(kv0 + rV[s2]) * cH + cV[s2],
                  (char*)&Vs[bufi][0] + (w * 2 + s2) * 1024);
    }
  };

  stage(0, 0);
  asm volatile("s_waitcnt vmcnt(0)" ::: "memory");
  __syncthreads();

  unsigned short* pw = &plds[w][0];  // pT[64][16]: elem = k*16 + q (swizzled)

  constexpr int NT = cS / 64;  // 32
  for (int kt = 0; kt < NT; ++kt) {
    const int bufi = kt & 1;
    if (kt + 1 < NT) stage(bufi ^ 1, (kt + 1) * 64);

    const unsigned short* Kt = &Ks[bufi][0];
    const unsigned short* Vt = &Vs[bufi][0];
    const int kv0 = kt * 64;

    // ---- QK^T from swizzled K LDS ----
    f32x4 sc[4];
#pragma unroll
    for (int n = 0; n < 4; ++n) {
      const int kr = n * 16 + lr;
      const unsigned sw = (unsigned)((kr & 7) << 4);
      const unsigned b0 = ((unsigned)(kr * 128 + lg * 16)) ^ sw;
      const unsigned b1 = ((unsigned)(kr * 128 + 64 + lg * 16)) ^ sw;
      short8 kf0 = *reinterpret_cast<const short8*>((const char*)Kt + b0);
      short8 kf1 = *reinterpret_cast<const short8*>((const char*)Kt + b1);
      f32x4 z = {0.f, 0.f, 0.f, 0.f};
      z = __builtin_amdgcn_mfma_f32_16x16x32_bf16(qf0, kf0, z, 0, 0, 0);
      z = __builtin_amdgcn_mfma_f32_16x16x32_bf16(qf1, kf1, z, 0, 0, 0);
      sc[n] = z * 0.125f + mbase[kv0 + kr];
    }

    // ---- online softmax: MAX only via shuffles (sum comes from MFMA) ----
    float scalef[4];
    unsigned short pb[4][4];  // [n][r]
#pragma unroll
    for (int r = 0; r < 4; ++r) {
      float mx = fmaxf(fmaxf(sc[0][r], sc[1][r]), fmaxf(sc[2][r], sc[3][r]));
#pragma unroll
      for (int d = 1; d < 16; d <<= 1) mx = fmaxf(mx, __shfl_xor(mx, d));
      const float mnew = fmaxf(mrow[r], mx);
      scalef[r] = __expf(mrow[r] - mnew);
      mrow[r] = mnew;
#pragma unroll
      for (int n = 0; n < 4; ++n) pb[n][r] = f2bf(__expf(sc[n][r] - mnew));
    }
#pragma unroll
    for (int d16 = 0; d16 < 4; ++d16)
#pragma unroll
      for (int r = 0; r < 4; ++r) oacc[d16][r] *= scalef[r];
#pragma unroll
    for (int r = 0; r < 4; ++r) osum[r] *= scalef[r];

    // ---- P^T -> per-wave LDS [64][16], bank-swizzled:
    //      logical colblk lg stored at physical lg ^ ((row>>2)&3) ----
    const int pcb = (lg ^ (lr >> 2)) * 4;  // (row>>2)&3 == lr>>2 for row=n*16+lr
#pragma unroll
    for (int n = 0; n < 4; ++n) {
      short4v v4 = {(short)pb[n][0], (short)pb[n][1], (short)pb[n][2],
                    (short)pb[n][3]};
      *reinterpret_cast<short4v*>(&pw[(n * 16 + lr) * 16 + pcb]) = v4;
    }
    asm volatile("s_waitcnt lgkmcnt(0)" ::: "memory");
    __builtin_amdgcn_sched_barrier(0);

    // ---- PV: A = P via tr16 on pT, B = V via tr16 (r7-verified) ----
#pragma unroll
    for (int ks2 = 0; ks2 < 2; ++ks2) {
      const int k0 = ks2 * 32 + lg * 8;
      const int key = (lg & 1) * 2;  // ((k0+j)>>2)&3 for j=0..3
      // lane lr reads physical colblk (lr&3)^key (rows k0..k0+3), and
      // (lr&3)^key^1 (rows k0+4..k0+7).
      short4v t0 = tr16(&pw[(k0 + (lr >> 2)) * 16 + (((lr & 3) ^ key) * 4)]);
      short4v t1 =
          tr16(&pw[(k0 + 4 + (lr >> 2)) * 16 + (((lr & 3) ^ key ^ 1) * 4)]);
      short4v tv[8];
#pragma unroll
      for (int d16 = 0; d16 < 4; ++d16) {
        const unsigned short* a0 =
            Vt + (ks2 * 8 + lg * 2) * 256 + d16 * 64 + lr * 4;
        tv[2 * d16] = tr16(a0);            // V rows k0..+3, col lr
        tv[2 * d16 + 1] = tr16(a0 + 256);  // V rows k0+4..+7, col lr
      }
      asm volatile("s_waitcnt lgkmcnt(0)" ::: "memory");
      __builtin_amdgcn_sched_barrier(0);
      short8 pa;
#pragma unroll
      for (int j = 0; j < 4; ++j) {
        pa[j] = t0[j];
        pa[4 + j] = t1[j];
      }
      osum = __builtin_amdgcn_mfma_f32_16x16x32_bf16(pa, ones, osum, 0, 0, 0);
#pragma unroll
      for (int d16 = 0; d16 < 4; ++d16) {
        short8 vf;
#pragma unroll
        for (int j = 0; j < 4; ++j) {
          vf[j] = tv[2 * d16][j];
          vf[4 + j] = tv[2 * d16 + 1][j];
        }
        oacc[d16] =
            __builtin_amdgcn_mfma_f32_16x16x32_bf16(pa, vf, oacc[d16], 0, 0, 0);
      }
    }

    asm volatile("s_waitcnt vmcnt(0)" ::: "memory");
    __syncthreads();  // staged tile kt+1 ready; all waves done with buf kt
  }

  // fp32 store; denominator from the MFMA row-sum accumulator
  float* obase = out + (size_t)(b * cS + q0 + lg * 4) * cH + h * cHD;
#pragma unroll
  for (int r = 0; r < 4; ++r) {
    const float inv = 1.0f / osum[r];
#pragma unroll
    for (int d16 = 0; d16 < 4; ++d16)
      obase[(size_t)r * cH + d16 * 16 + lr] = oacc[d16][r] * inv;
  }
}

// ---------------- launcher ----------------
extern "C" void kernel_launch(void* const* d_in, const int* in_sizes, int n_in,
                              void* d_out, int out_size, void* d_ws,
                              size_t ws_size, hipStream_t stream) {
  const float* X = (const float*)d_in[0];     // [B,S,H]
  const float* mask = (const float*)d_in[1];  // [B,1,1,S]
  const float* Wq = (const float*)d_in[2];
  const float* bq = (const float*)d_in[3];
  const float* Wk = (const float*)d_in[4];
  const float* bk = (const float*)d_in[5];
  const float* Wv = (const float*)d_in[6];
  const float* bv = (const float*)d_in[7];
  float* outp = (float*)d_out;  // fp32 (reference output dtype)

  // workspace: Q,K,V bf16 -> 24 MB total
  char* ws = (char*)d_ws;
  const size_t MB = 1 << 20;
  unsigned short* Qb = (unsigned short*)(ws + 0 * MB);   // 8 MB
  unsigned short* Kb = (unsigned short*)(ws + 8 * MB);   // 8 MB
  unsigned short* Vb = (unsigned short*)(ws + 16 * MB);  // 8 MB

  qkv_gemm<<<dim3(24, 32), 256, 0, stream>>>(X, Wq, Wk, Wv, bq, bk, bv, Qb, Kb,
                                             Vb);
  attn_kernel<<<dim3(32, 32), 256, 0, stream>>>(Qb, Kb, Vb, mask, outp);
}